// Round 2
// baseline (145.981 us; speedup 1.0000x reference)
//
#include <hip/hip_runtime.h>

#define NP      4096
#define WINDOW  327
#define HALF    163
#define RL      20
#define NA      262144
#define GN_EPS  1e-6f
#define R       4          // rows (bins) per block
#define NBLK    (NP / R)   // 1024 blocks
#define NT      512        // 8 waves/block -> 8 waves/SIMD at 4 blocks/CU

// fast tanh: 1 - 2/(e^{2x}+1), ~1e-7 abs err
__device__ __forceinline__ float tanh_fast(float x) {
  float e = __expf(2.0f * x);
  return 1.0f - 2.0f / (e + 1.0f);
}

// full-wave (64-lane) butterfly sum of two values
__device__ __forceinline__ void wave_sum2(float& a, float& b) {
#pragma unroll
  for (int m = 1; m < 64; m <<= 1) {
    a += __shfl_xor(a, m, 64);
    b += __shfl_xor(b, m, 64);
  }
}

// LDS layout (floats). part overlays espan+obsT (dead after L0, barrier-separated).
#define L_ESP   0               // espan[330]      (lifetime: A..L0)
#define L_OBS   332             // obsT[40][4]     (lifetime: B..L0)
#define L_PART  0               // part[8][4][256] = 8192  (lifetime: post-L0..GN1)
#define L_HBUF  8192            // hbuf[4][260]
#define L_HCL   9232            // hcL[4][36]
#define L_TOT   9376            // 37.5 KB -> 4 blocks/CU

__global__ __launch_bounds__(NT, 8) void dc_table(
    const float* __restrict__ zc,  const float* __restrict__ zt,
    const float* __restrict__ bW0, const float* __restrict__ bb0,
    const float* __restrict__ bs0, const float* __restrict__ bB0,
    const float* __restrict__ bW1, const float* __restrict__ bb1,
    const float* __restrict__ bs1, const float* __restrict__ bB1,
    const float* __restrict__ tW0, const float* __restrict__ tb0,
    const float* __restrict__ tW1, const float* __restrict__ tb1,
    const float* __restrict__ cW,  const float* __restrict__ cb,
    const float* __restrict__ uW,  const float* __restrict__ ub,
    const float* __restrict__ vW,  const float* __restrict__ vb,
    float* __restrict__ tbl)
{
  __shared__ __align__(16) float sm[L_TOT];
  float* espan = sm + L_ESP;
  float* obsT  = sm + L_OBS;    // [k][r], stride 4
  float* part  = sm + L_PART;   // [w][r][f]
  float* hbuf  = sm + L_HBUF;   // [r][f], stride 260
  float* hcL   = sm + L_HCL;    // [r][c], stride 36

  const int tid = threadIdx.x;
  const int w   = tid >> 6;     // 0..7
  const int l   = tid & 63;
  const int s0  = blockIdx.x * R;

  // ---- Phase A: shared error span (edge-clamped), 330 elems ----
  if (tid < WINDOW + R - 1) {
    int c = s0 - HALF + tid;
    c = c < 0 ? 0 : (c > NP - 1 ? NP - 1 : c);
    espan[tid] = zc[c] - zt[c];
  }
  __syncthreads();

  // ---- Phase B: bilinear-antialias resize of err & gradient -> obsT[40][4] ----
  if (tid < R * 2 * RL) {
    const float INV  = (float)WINDOW / (float)RL;   // 16.35
    const float RINV = (float)RL / (float)WINDOW;
    int q = tid % (2 * RL);
    int r = tid / (2 * RL);
    int qq = (q < RL) ? q : q - RL;
    float xs = ((float)qq + 0.5f) * INV - 0.5f;
    int jlo = (int)ceilf(xs - INV);  if (jlo < 0) jlo = 0;
    int jhi = (int)floorf(xs + INV); if (jhi > WINDOW - 1) jhi = WINDOW - 1;
    const float* p = espan + r;
    float wsum = 0.0f, acc = 0.0f;
    for (int j = jlo; j <= jhi; ++j) {
      float wq = 1.0f - fabsf(xs - (float)j) * RINV;
      float v;
      if (q < RL) {
        v = p[j];
      } else {
        v = (j == 0) ? (p[1] - p[0]) :
            (j == WINDOW - 1) ? (p[WINDOW - 1] - p[WINDOW - 2]) :
            0.5f * (p[j + 1] - p[j - 1]);
      }
      wsum += wq;
      acc  += wq * v;
    }
    obsT[q * 4 + r] = acc / wsum;
  }
  __syncthreads();

  float acc[R][4];

  // ---- Layer 0 (40 -> 256), k-split: wave w owns k in [5w, 5w+5) ----
#pragma unroll
  for (int r = 0; r < R; ++r) { acc[r][0]=0.f; acc[r][1]=0.f; acc[r][2]=0.f; acc[r][3]=0.f; }
  for (int kk = 0; kk < 5; ++kk) {
    int k = w * 5 + kk;
    float4 wt = *(const float4*)&bW0[k * 256 + 4 * l];
    float4 o  = *(const float4*)&obsT[k * 4];
    const float wv[4] = {wt.x, wt.y, wt.z, wt.w};
    const float ov[4] = {o.x, o.y, o.z, o.w};
#pragma unroll
    for (int r = 0; r < R; ++r)
#pragma unroll
      for (int j = 0; j < 4; ++j) acc[r][j] = fmaf(ov[r], wv[j], acc[r][j]);
  }
  __syncthreads();   // espan/obsT reads complete before part overwrites them

  // ---- combine + GN0 + tanh -> hbuf (waves 0-3, one per row) ----
#pragma unroll
  for (int r = 0; r < R; ++r)
    *(float4*)&part[w * 1024 + r * 256 + 4 * l] = make_float4(acc[r][0], acc[r][1], acc[r][2], acc[r][3]);
  __syncthreads();
  if (w < 4) {
    int rr = w, g = l;
    float4 b0 = *(const float4*)&bb0[4 * g];
    float val[4] = {b0.x, b0.y, b0.z, b0.w};
#pragma unroll
    for (int w2 = 0; w2 < 8; ++w2) {
      float4 p0 = *(const float4*)&part[w2 * 1024 + rr * 256 + 4 * g];
      val[0]+=p0.x; val[1]+=p0.y; val[2]+=p0.z; val[3]+=p0.w;
    }
    float s = 0.f, q = 0.f;
#pragma unroll
    for (int i = 0; i < 4; ++i) { s += val[i]; q += val[i] * val[i]; }
    wave_sum2(s, q);
    float mu  = s * (1.0f / 256.0f);
    float var = fmaxf(q * (1.0f / 256.0f) - mu * mu, 0.0f);
    float rv  = rsqrtf(var + GN_EPS);
    float4 sc0 = *(const float4*)&bs0[4 * g];
    float4 sh0 = *(const float4*)&bB0[4 * g];
    const float sc[4] = {sc0.x,sc0.y,sc0.z,sc0.w};
    const float sh[4] = {sh0.x,sh0.y,sh0.z,sh0.w};
    float h[4];
#pragma unroll
    for (int i = 0; i < 4; ++i) h[i] = tanh_fast((val[i] - mu) * rv * sc[i] + sh[i]);
    *(float4*)&hbuf[rr * 260 + 4 * g] = make_float4(h[0], h[1], h[2], h[3]);
  }
  __syncthreads();

  // ---- Layer 1 (256 -> 256), k-split: wave w owns k in [32w, 32w+32) ----
#pragma unroll
  for (int r = 0; r < R; ++r) { acc[r][0]=0.f; acc[r][1]=0.f; acc[r][2]=0.f; acc[r][3]=0.f; }
  for (int kk = 0; kk < 32; kk += 4) {
    int k0 = w * 32 + kk;
    float4 wt0 = *(const float4*)&bW1[(k0    ) * 256 + 4 * l];
    float4 wt1 = *(const float4*)&bW1[(k0 + 1) * 256 + 4 * l];
    float4 wt2 = *(const float4*)&bW1[(k0 + 2) * 256 + 4 * l];
    float4 wt3 = *(const float4*)&bW1[(k0 + 3) * 256 + 4 * l];
    float4 hr[R];
#pragma unroll
    for (int r = 0; r < R; ++r) hr[r] = *(const float4*)&hbuf[r * 260 + k0];
#pragma unroll
    for (int r = 0; r < R; ++r) {
      const float* hp = (const float*)&hr[r];
      acc[r][0] = fmaf(hp[0], wt0.x, acc[r][0]); acc[r][1] = fmaf(hp[0], wt0.y, acc[r][1]);
      acc[r][2] = fmaf(hp[0], wt0.z, acc[r][2]); acc[r][3] = fmaf(hp[0], wt0.w, acc[r][3]);
      acc[r][0] = fmaf(hp[1], wt1.x, acc[r][0]); acc[r][1] = fmaf(hp[1], wt1.y, acc[r][1]);
      acc[r][2] = fmaf(hp[1], wt1.z, acc[r][2]); acc[r][3] = fmaf(hp[1], wt1.w, acc[r][3]);
      acc[r][0] = fmaf(hp[2], wt2.x, acc[r][0]); acc[r][1] = fmaf(hp[2], wt2.y, acc[r][1]);
      acc[r][2] = fmaf(hp[2], wt2.z, acc[r][2]); acc[r][3] = fmaf(hp[2], wt2.w, acc[r][3]);
      acc[r][0] = fmaf(hp[3], wt3.x, acc[r][0]); acc[r][1] = fmaf(hp[3], wt3.y, acc[r][1]);
      acc[r][2] = fmaf(hp[3], wt3.z, acc[r][2]); acc[r][3] = fmaf(hp[3], wt3.w, acc[r][3]);
    }
  }

  // ---- combine + GN1 + tanh -> hbuf (part write races nothing: hbuf!=part) ----
#pragma unroll
  for (int r = 0; r < R; ++r)
    *(float4*)&part[w * 1024 + r * 256 + 4 * l] = make_float4(acc[r][0], acc[r][1], acc[r][2], acc[r][3]);
  __syncthreads();
  if (w < 4) {
    int rr = w, g = l;
    float4 b0 = *(const float4*)&bb1[4 * g];
    float val[4] = {b0.x, b0.y, b0.z, b0.w};
#pragma unroll
    for (int w2 = 0; w2 < 8; ++w2) {
      float4 p0 = *(const float4*)&part[w2 * 1024 + rr * 256 + 4 * g];
      val[0]+=p0.x; val[1]+=p0.y; val[2]+=p0.z; val[3]+=p0.w;
    }
    float s = 0.f, q = 0.f;
#pragma unroll
    for (int i = 0; i < 4; ++i) { s += val[i]; q += val[i] * val[i]; }
    wave_sum2(s, q);
    float mu  = s * (1.0f / 256.0f);
    float var = fmaxf(q * (1.0f / 256.0f) - mu * mu, 0.0f);
    float rv  = rsqrtf(var + GN_EPS);
    float4 sc0 = *(const float4*)&bs1[4 * g];
    float4 sh0 = *(const float4*)&bB1[4 * g];
    const float sc[4] = {sc0.x,sc0.y,sc0.z,sc0.w};
    const float sh[4] = {sh0.x,sh0.y,sh0.z,sh0.w};
    float h[4];
#pragma unroll
    for (int i = 0; i < 4; ++i) h[i] = tanh_fast((val[i] - mu) * rv * sc[i] + sh[i]);
    *(float4*)&hbuf[rr * 260 + 4 * g] = make_float4(h[0], h[1], h[2], h[3]);
  }
  __syncthreads();

  // ---- Phase G: hcL[r][c..c+4) = cb + h1[r,:] . cW[:,c..c+4)
  //      waves 0-3 (one per row); lane = (kg = l>>3 k-group of 32, c4 = l&7 col-quad)
  //      cW loaded as float4 rows (8 lanes = 128B contiguous); kg-staggered hbuf reads ----
  if (w < 4) {
    int r  = w;
    int kg = l >> 3;
    int c  = (l & 7) * 4;
    float ga0 = 0.f, ga1 = 0.f, ga2 = 0.f, ga3 = 0.f;
#pragma unroll
    for (int ii = 0; ii < 8; ++ii) {
      int j  = (ii + kg) & 7;              // stagger: conflict-free hbuf banks
      int kb = kg * 32 + 4 * j;
      float4 hv = *(const float4*)&hbuf[r * 260 + kb];
      const float hvv[4] = {hv.x, hv.y, hv.z, hv.w};
#pragma unroll
      for (int i2 = 0; i2 < 4; ++i2) {
        float4 cw = *(const float4*)&cW[(kb + i2) * 32 + c];
        ga0 = fmaf(hvv[i2], cw.x, ga0);
        ga1 = fmaf(hvv[i2], cw.y, ga1);
        ga2 = fmaf(hvv[i2], cw.z, ga2);
        ga3 = fmaf(hvv[i2], cw.w, ga3);
      }
    }
#pragma unroll
    for (int m = 8; m < 64; m <<= 1) {
      ga0 += __shfl_xor(ga0, m, 64);
      ga1 += __shfl_xor(ga1, m, 64);
      ga2 += __shfl_xor(ga2, m, 64);
      ga3 += __shfl_xor(ga3, m, 64);
    }
    if (l < 8) {
      float4 cbv = *(const float4*)&cb[c];
      *(float4*)&hcL[r * 36 + c] = make_float4(ga0 + cbv.x, ga1 + cbv.y, ga2 + cbv.z, ga3 + cbv.w);
    }
  }
  __syncthreads();

  // ---- Tail: 8 endpoint evals (4 bins x {left,right}), 8 threads each -> wave 0 ----
  if (tid < 64) {
    int v = tid >> 3, sub = tid & 7;
    int r = v >> 1, e = v & 1;
    int jg = s0 + r + e;                      // grid point; hc stays hcL[r]
    float xe = (float)jg * (1.0f / 4095.0f);
    float enc[8];
#pragma unroll
    for (int k = 0; k < 4; ++k) {
      float fr = (float)(1 << k);
      float a = (xe * fr) * 3.14159265358979f;
      enc[k]     = sinf(a);
      enc[k + 4] = cosf(a);
    }
    int base = tid & ~7;                      // octet base lane within wave

    float t0v[4];
#pragma unroll
    for (int i = 0; i < 4; ++i) {
      int f = 4 * sub + i;
      float a = tb0[f];
#pragma unroll
      for (int k = 0; k < 8; ++k) a = fmaf(enc[k], tW0[k * 32 + f], a);
      t0v[i] = tanh_fast(a);
    }

    float t1v[4];
#pragma unroll
    for (int i = 0; i < 4; ++i) t1v[i] = tb1[4 * sub + i];
#pragma unroll
    for (int j8 = 0; j8 < 8; ++j8) {
#pragma unroll
      for (int i2 = 0; i2 < 4; ++i2) {
        float tv = __shfl(t0v[i2], base + j8, 64);
        int k = 4 * j8 + i2;
#pragma unroll
        for (int i = 0; i < 4; ++i) t1v[i] = fmaf(tv, tW1[k * 32 + 4 * sub + i], t1v[i]);
      }
    }
#pragma unroll
    for (int i = 0; i < 4; ++i) t1v[i] = tanh_fast(t1v[i]);

    float xvv[4];
#pragma unroll
    for (int i = 0; i < 4; ++i) xvv[i] = hcL[r * 36 + 4 * sub + i];
#pragma unroll
    for (int j8 = 0; j8 < 8; ++j8) {
#pragma unroll
      for (int i2 = 0; i2 < 4; ++i2) {
        float tv = __shfl(t1v[i2], base + j8, 64);
        int k = 4 * j8 + i2;
#pragma unroll
        for (int i = 0; i < 4; ++i) xvv[i] = fmaf(tv, cW[(256 + k) * 32 + 4 * sub + i], xvv[i]);
      }
    }
#pragma unroll
    for (int i = 0; i < 4; ++i) xvv[i] = tanh_fast(xvv[i]);

    float up = 0.f, vp = 0.f;
#pragma unroll
    for (int i = 0; i < 4; ++i) {
      up = fmaf(xvv[i], uW[4 * sub + i], up);
      vp = fmaf(xvv[i], vW[4 * sub + i], vp);
    }
#pragma unroll
    for (int m = 1; m < 8; m <<= 1) {
      up += __shfl_xor(up, m, 64);
      vp += __shfl_xor(vp, m, 64);
    }
    if (sub == 0) {
      int s = s0 + r;
      tbl[4 * s + e]     = 40.0f * tanh_fast(up + ub[0]);
      tbl[4 * s + 2 + e] = tanh_fast(vp + vb[0]);
    }
  }
}

// ---------------- Kernel 2: agents = bin + lerp ----------------
__global__ __launch_bounds__(256) void dc_agents(
    const float* __restrict__ xi_curr, const float4* __restrict__ tbl,
    float* __restrict__ out)
{
  int a = blockIdx.x * 256 + threadIdx.x;
  float xi = xi_curr[a];
  float p = xi * 4095.0f;           // same fp32 product the reference truncates
  int s = (int)p;
  s = s > 4095 ? 4095 : s;
  float t = p - (float)s;           // exact (Sterbenz)
  float4 tb = tbl[s];               // {u_l, u_r, v_l, v_r}
  out[a]      = fmaf(t, tb.y - tb.x, tb.x);
  out[NA + a] = fmaf(t, tb.w - tb.z, tb.z);
}

extern "C" void kernel_launch(void* const* d_in, const int* in_sizes, int n_in,
                              void* d_out, int out_size, void* d_ws, size_t ws_size,
                              hipStream_t stream) {
  const float* zc  = (const float*)d_in[0];
  const float* zt  = (const float*)d_in[1];
  const float* xi  = (const float*)d_in[2];
  const float* bW0 = (const float*)d_in[3];
  const float* bb0 = (const float*)d_in[4];
  const float* bs0 = (const float*)d_in[5];
  const float* bB0 = (const float*)d_in[6];
  const float* bW1 = (const float*)d_in[7];
  const float* bb1 = (const float*)d_in[8];
  const float* bs1 = (const float*)d_in[9];
  const float* bB1 = (const float*)d_in[10];
  const float* tW0 = (const float*)d_in[11];
  const float* tb0 = (const float*)d_in[12];
  const float* tW1 = (const float*)d_in[13];
  const float* tb1 = (const float*)d_in[14];
  const float* cW  = (const float*)d_in[15];
  const float* cb  = (const float*)d_in[16];
  const float* uW  = (const float*)d_in[17];
  const float* ub  = (const float*)d_in[18];
  const float* vW  = (const float*)d_in[19];
  const float* vb  = (const float*)d_in[20];

  float* tbl = (float*)d_ws;        // 4096 x float4 = 64 KB
  float* out = (float*)d_out;

  dc_table<<<NBLK, NT, 0, stream>>>(zc, zt, bW0, bb0, bs0, bB0,
                                    bW1, bb1, bs1, bB1,
                                    tW0, tb0, tW1, tb1, cW, cb,
                                    uW, ub, vW, vb, tbl);
  dc_agents<<<NA / 256, 256, 0, stream>>>(xi, (const float4*)tbl, out);
}

// Round 3
// 129.157 us; speedup vs baseline: 1.1303x; 1.1303x over previous
//
#include <hip/hip_runtime.h>

#define NP      4096
#define WINDOW  327
#define HALF    163
#define RL      20
#define NA      262144
#define GN_EPS  1e-6f
#define R       8          // rows (bins) per block
#define NBLK    (NP / R)   // 512 blocks
#define NT      256        // 4 waves/block

// fast tanh: 1 - 2/(e^{2x}+1), ~1e-7 abs err
__device__ __forceinline__ float tanh_fast(float x) {
  float e = __expf(2.0f * x);
  return 1.0f - 2.0f / (e + 1.0f);
}

// full-wave (64-lane) butterfly sum of two values
__device__ __forceinline__ void wave_sum2(float& a, float& b) {
#pragma unroll
  for (int m = 1; m < 64; m <<= 1) {
    a += __shfl_xor(a, m, 64);
    b += __shfl_xor(b, m, 64);
  }
}

// LDS layout (floats). part overlays espan+obsT (dead after L0, barrier-separated).
#define L_ESP   0               // espan[336]  (need 334; lifetime A..L0)
#define L_OBS   336             // obsT[40][8] (lifetime B..L0)
#define L_PART  0               // part[4][4][256] = 4096 (2-pass; lifetime post-L0..GN1)
#define L_HBUF  4096            // hbuf[8][260] = 2080
#define L_HCL   6176            // hcL[8][36]  = 288
#define L_TOT   6464            // 25.9 KB -> LDS allows 6 blocks/CU; VGPR decides

__global__ __launch_bounds__(NT, 3) void dc_table(
    const float* __restrict__ zc,  const float* __restrict__ zt,
    const float* __restrict__ bW0, const float* __restrict__ bb0,
    const float* __restrict__ bs0, const float* __restrict__ bB0,
    const float* __restrict__ bW1, const float* __restrict__ bb1,
    const float* __restrict__ bs1, const float* __restrict__ bB1,
    const float* __restrict__ tW0, const float* __restrict__ tb0,
    const float* __restrict__ tW1, const float* __restrict__ tb1,
    const float* __restrict__ cW,  const float* __restrict__ cb,
    const float* __restrict__ uW,  const float* __restrict__ ub,
    const float* __restrict__ vW,  const float* __restrict__ vb,
    float* __restrict__ tbl)
{
  __shared__ __align__(16) float sm[L_TOT];
  float* espan = sm + L_ESP;
  float* obsT  = sm + L_OBS;    // [k][r], stride 8
  float* part  = sm + L_PART;   // [w][r4][f]
  float* hbuf  = sm + L_HBUF;   // [r][f], stride 260
  float* hcL   = sm + L_HCL;    // [r][c], stride 36

  const int tid = threadIdx.x;
  const int w   = tid >> 6;     // 0..3
  const int l   = tid & 63;
  const int s0  = blockIdx.x * R;

  // ---- Phase A: shared error span (edge-clamped), 334 elems ----
  for (int t = tid; t < WINDOW + R - 1; t += NT) {
    int c = s0 - HALF + t;
    c = c < 0 ? 0 : (c > NP - 1 ? NP - 1 : c);
    espan[t] = zc[c] - zt[c];
  }
  __syncthreads();

  // ---- Phase B: bilinear-antialias resize of err & gradient -> obsT[40][8] ----
  {
    const float INV  = (float)WINDOW / (float)RL;   // 16.35
    const float RINV = (float)RL / (float)WINDOW;
    for (int task = tid; task < R * 2 * RL; task += NT) {
      int q = task % (2 * RL);
      int r = task / (2 * RL);
      int qq = (q < RL) ? q : q - RL;
      float xs = ((float)qq + 0.5f) * INV - 0.5f;
      int jlo = (int)ceilf(xs - INV);  if (jlo < 0) jlo = 0;
      int jhi = (int)floorf(xs + INV); if (jhi > WINDOW - 1) jhi = WINDOW - 1;
      const float* p = espan + r;
      float wsum = 0.0f, acc = 0.0f;
      for (int j = jlo; j <= jhi; ++j) {
        float wq = 1.0f - fabsf(xs - (float)j) * RINV;
        float v;
        if (q < RL) {
          v = p[j];
        } else {
          v = (j == 0) ? (p[1] - p[0]) :
              (j == WINDOW - 1) ? (p[WINDOW - 1] - p[WINDOW - 2]) :
              0.5f * (p[j + 1] - p[j - 1]);
        }
        wsum += wq;
        acc  += wq * v;
      }
      obsT[q * 8 + r] = acc / wsum;
    }
  }
  __syncthreads();

  float acc[R][4];

  // ---- Layer 0 (40 -> 256), k-split: wave w owns k in [10w, 10w+10) ----
#pragma unroll
  for (int r = 0; r < R; ++r) { acc[r][0]=0.f; acc[r][1]=0.f; acc[r][2]=0.f; acc[r][3]=0.f; }
  for (int kk = 0; kk < 10; ++kk) {
    int k = w * 10 + kk;
    float4 wt = *(const float4*)&bW0[k * 256 + 4 * l];
    float4 o0 = *(const float4*)&obsT[k * 8];
    float4 o1 = *(const float4*)&obsT[k * 8 + 4];
    const float wv[4] = {wt.x, wt.y, wt.z, wt.w};
    const float ov[8] = {o0.x, o0.y, o0.z, o0.w, o1.x, o1.y, o1.z, o1.w};
#pragma unroll
    for (int r = 0; r < R; ++r)
#pragma unroll
      for (int j = 0; j < 4; ++j) acc[r][j] = fmaf(ov[r], wv[j], acc[r][j]);
  }
  __syncthreads();   // espan/obsT reads complete before part overwrites them

  // ---- GN0 + tanh -> hbuf, two passes of 4 rows (part = 16 KB reused) ----
#pragma unroll
  for (int p = 0; p < 2; ++p) {
#pragma unroll
    for (int r = 0; r < 4; ++r)
      *(float4*)&part[w * 1024 + r * 256 + 4 * l] =
        make_float4(acc[4*p+r][0], acc[4*p+r][1], acc[4*p+r][2], acc[4*p+r][3]);
    __syncthreads();
    {
      int row = 4 * p + w;                  // wave w owns one row per pass
      float4 b0 = *(const float4*)&bb0[4 * l];
      float val[4] = {b0.x, b0.y, b0.z, b0.w};
#pragma unroll
      for (int w2 = 0; w2 < 4; ++w2) {
        float4 p0 = *(const float4*)&part[w2 * 1024 + w * 256 + 4 * l];
        val[0]+=p0.x; val[1]+=p0.y; val[2]+=p0.z; val[3]+=p0.w;
      }
      float s = 0.f, q = 0.f;
#pragma unroll
      for (int i = 0; i < 4; ++i) { s += val[i]; q += val[i] * val[i]; }
      wave_sum2(s, q);
      float mu  = s * (1.0f / 256.0f);
      float var = fmaxf(q * (1.0f / 256.0f) - mu * mu, 0.0f);
      float rv  = rsqrtf(var + GN_EPS);
      float4 sc0 = *(const float4*)&bs0[4 * l];
      float4 sh0 = *(const float4*)&bB0[4 * l];
      const float sc[4] = {sc0.x,sc0.y,sc0.z,sc0.w};
      const float sh[4] = {sh0.x,sh0.y,sh0.z,sh0.w};
      float h[4];
#pragma unroll
      for (int i = 0; i < 4; ++i) h[i] = tanh_fast((val[i] - mu) * rv * sc[i] + sh[i]);
      *(float4*)&hbuf[row * 260 + 4 * l] = make_float4(h[0], h[1], h[2], h[3]);
    }
    __syncthreads();
  }

  // ---- Layer 1 (256 -> 256), k-split: wave w owns k in [64w, 64w+64)
  //      8-deep weight pipeline: 8 float4 global loads in flight per chunk ----
#pragma unroll
  for (int r = 0; r < R; ++r) { acc[r][0]=0.f; acc[r][1]=0.f; acc[r][2]=0.f; acc[r][3]=0.f; }
  for (int kk = 0; kk < 64; kk += 8) {
    int k0 = w * 64 + kk;
    float4 wt[8];
#pragma unroll
    for (int j = 0; j < 8; ++j) wt[j] = *(const float4*)&bW1[(k0 + j) * 256 + 4 * l];
#pragma unroll
    for (int half = 0; half < 2; ++half) {
      int kb = k0 + 4 * half;
      float4 hr[R];
#pragma unroll
      for (int r = 0; r < R; ++r) hr[r] = *(const float4*)&hbuf[r * 260 + kb];
#pragma unroll
      for (int r = 0; r < R; ++r) {
        const float* hp = (const float*)&hr[r];
#pragma unroll
        for (int j = 0; j < 4; ++j) {
          const float4& wv = wt[4 * half + j];
          acc[r][0] = fmaf(hp[j], wv.x, acc[r][0]);
          acc[r][1] = fmaf(hp[j], wv.y, acc[r][1]);
          acc[r][2] = fmaf(hp[j], wv.z, acc[r][2]);
          acc[r][3] = fmaf(hp[j], wv.w, acc[r][3]);
        }
      }
    }
  }

  // ---- GN1 + tanh -> hbuf, two passes of 4 rows ----
#pragma unroll
  for (int p = 0; p < 2; ++p) {
#pragma unroll
    for (int r = 0; r < 4; ++r)
      *(float4*)&part[w * 1024 + r * 256 + 4 * l] =
        make_float4(acc[4*p+r][0], acc[4*p+r][1], acc[4*p+r][2], acc[4*p+r][3]);
    __syncthreads();
    {
      int row = 4 * p + w;
      float4 b0 = *(const float4*)&bb1[4 * l];
      float val[4] = {b0.x, b0.y, b0.z, b0.w};
#pragma unroll
      for (int w2 = 0; w2 < 4; ++w2) {
        float4 p0 = *(const float4*)&part[w2 * 1024 + w * 256 + 4 * l];
        val[0]+=p0.x; val[1]+=p0.y; val[2]+=p0.z; val[3]+=p0.w;
      }
      float s = 0.f, q = 0.f;
#pragma unroll
      for (int i = 0; i < 4; ++i) { s += val[i]; q += val[i] * val[i]; }
      wave_sum2(s, q);
      float mu  = s * (1.0f / 256.0f);
      float var = fmaxf(q * (1.0f / 256.0f) - mu * mu, 0.0f);
      float rv  = rsqrtf(var + GN_EPS);
      float4 sc0 = *(const float4*)&bs1[4 * l];
      float4 sh0 = *(const float4*)&bB1[4 * l];
      const float sc[4] = {sc0.x,sc0.y,sc0.z,sc0.w};
      const float sh[4] = {sh0.x,sh0.y,sh0.z,sh0.w};
      float h[4];
#pragma unroll
      for (int i = 0; i < 4; ++i) h[i] = tanh_fast((val[i] - mu) * rv * sc[i] + sh[i]);
      *(float4*)&hbuf[row * 260 + 4 * l] = make_float4(h[0], h[1], h[2], h[3]);
    }
    __syncthreads();
  }

  // ---- Phase G: hcL[r][c..c+4) = cb + h1[r,:] . cW[:,c..c+4)
  //      wave w handles rows {w, w+4}; lane = (kg = l>>3, c4 = l&7)
  //      cW as float4 rows (8 lanes = 128B contiguous); kg-staggered hbuf reads ----
#pragma unroll
  for (int rp = 0; rp < 2; ++rp) {
    int r  = w + 4 * rp;
    int kg = l >> 3;
    int c  = (l & 7) * 4;
    float ga0 = 0.f, ga1 = 0.f, ga2 = 0.f, ga3 = 0.f;
#pragma unroll
    for (int ii = 0; ii < 8; ++ii) {
      int j  = (ii + kg) & 7;              // stagger: conflict-free hbuf banks
      int kb = kg * 32 + 4 * j;
      float4 hv = *(const float4*)&hbuf[r * 260 + kb];
      const float hvv[4] = {hv.x, hv.y, hv.z, hv.w};
#pragma unroll
      for (int i2 = 0; i2 < 4; ++i2) {
        float4 cw = *(const float4*)&cW[(kb + i2) * 32 + c];
        ga0 = fmaf(hvv[i2], cw.x, ga0);
        ga1 = fmaf(hvv[i2], cw.y, ga1);
        ga2 = fmaf(hvv[i2], cw.z, ga2);
        ga3 = fmaf(hvv[i2], cw.w, ga3);
      }
    }
#pragma unroll
    for (int m = 8; m < 64; m <<= 1) {
      ga0 += __shfl_xor(ga0, m, 64);
      ga1 += __shfl_xor(ga1, m, 64);
      ga2 += __shfl_xor(ga2, m, 64);
      ga3 += __shfl_xor(ga3, m, 64);
    }
    if (l < 8) {
      float4 cbv = *(const float4*)&cb[c];
      *(float4*)&hcL[r * 36 + c] = make_float4(ga0 + cbv.x, ga1 + cbv.y, ga2 + cbv.z, ga3 + cbv.w);
    }
  }
  __syncthreads();

  // ---- Tail: 16 endpoint evals (8 bins x {left,right}), 8 threads each ----
  if (tid < 128) {
    int v = tid >> 3, sub = tid & 7;
    int r = v >> 1, e = v & 1;
    int jg = s0 + r + e;                      // grid point; hc stays hcL[r]
    float xe = (float)jg * (1.0f / 4095.0f);
    float enc[8];
#pragma unroll
    for (int k = 0; k < 4; ++k) {
      float fr = (float)(1 << k);
      float a = (xe * fr) * 3.14159265358979f;
      enc[k]     = sinf(a);
      enc[k + 4] = cosf(a);
    }
    int base = (tid & 63) & ~7;               // octet base lane within wave

    float t0v[4];
#pragma unroll
    for (int i = 0; i < 4; ++i) {
      int f = 4 * sub + i;
      float a = tb0[f];
#pragma unroll
      for (int k = 0; k < 8; ++k) a = fmaf(enc[k], tW0[k * 32 + f], a);
      t0v[i] = tanh_fast(a);
    }

    float t1v[4];
#pragma unroll
    for (int i = 0; i < 4; ++i) t1v[i] = tb1[4 * sub + i];
#pragma unroll
    for (int j8 = 0; j8 < 8; ++j8) {
#pragma unroll
      for (int i2 = 0; i2 < 4; ++i2) {
        float tv = __shfl(t0v[i2], base + j8, 64);
        int k = 4 * j8 + i2;
#pragma unroll
        for (int i = 0; i < 4; ++i) t1v[i] = fmaf(tv, tW1[k * 32 + 4 * sub + i], t1v[i]);
      }
    }
#pragma unroll
    for (int i = 0; i < 4; ++i) t1v[i] = tanh_fast(t1v[i]);

    float xvv[4];
#pragma unroll
    for (int i = 0; i < 4; ++i) xvv[i] = hcL[r * 36 + 4 * sub + i];
#pragma unroll
    for (int j8 = 0; j8 < 8; ++j8) {
#pragma unroll
      for (int i2 = 0; i2 < 4; ++i2) {
        float tv = __shfl(t1v[i2], base + j8, 64);
        int k = 4 * j8 + i2;
#pragma unroll
        for (int i = 0; i < 4; ++i) xvv[i] = fmaf(tv, cW[(256 + k) * 32 + 4 * sub + i], xvv[i]);
      }
    }
#pragma unroll
    for (int i = 0; i < 4; ++i) xvv[i] = tanh_fast(xvv[i]);

    float up = 0.f, vp = 0.f;
#pragma unroll
    for (int i = 0; i < 4; ++i) {
      up = fmaf(xvv[i], uW[4 * sub + i], up);
      vp = fmaf(xvv[i], vW[4 * sub + i], vp);
    }
#pragma unroll
    for (int m = 1; m < 8; m <<= 1) {
      up += __shfl_xor(up, m, 64);
      vp += __shfl_xor(vp, m, 64);
    }
    if (sub == 0) {
      int s = s0 + r;
      tbl[4 * s + e]     = 40.0f * tanh_fast(up + ub[0]);
      tbl[4 * s + 2 + e] = tanh_fast(vp + vb[0]);
    }
  }
}

// ---------------- Kernel 2: agents = bin + lerp ----------------
__global__ __launch_bounds__(256) void dc_agents(
    const float* __restrict__ xi_curr, const float4* __restrict__ tbl,
    float* __restrict__ out)
{
  int a = blockIdx.x * 256 + threadIdx.x;
  float xi = xi_curr[a];
  float p = xi * 4095.0f;           // same fp32 product the reference truncates
  int s = (int)p;
  s = s > 4095 ? 4095 : s;
  float t = p - (float)s;           // exact (Sterbenz)
  float4 tb = tbl[s];               // {u_l, u_r, v_l, v_r}
  out[a]      = fmaf(t, tb.y - tb.x, tb.x);
  out[NA + a] = fmaf(t, tb.w - tb.z, tb.z);
}

extern "C" void kernel_launch(void* const* d_in, const int* in_sizes, int n_in,
                              void* d_out, int out_size, void* d_ws, size_t ws_size,
                              hipStream_t stream) {
  const float* zc  = (const float*)d_in[0];
  const float* zt  = (const float*)d_in[1];
  const float* xi  = (const float*)d_in[2];
  const float* bW0 = (const float*)d_in[3];
  const float* bb0 = (const float*)d_in[4];
  const float* bs0 = (const float*)d_in[5];
  const float* bB0 = (const float*)d_in[6];
  const float* bW1 = (const float*)d_in[7];
  const float* bb1 = (const float*)d_in[8];
  const float* bs1 = (const float*)d_in[9];
  const float* bB1 = (const float*)d_in[10];
  const float* tW0 = (const float*)d_in[11];
  const float* tb0 = (const float*)d_in[12];
  const float* tW1 = (const float*)d_in[13];
  const float* tb1 = (const float*)d_in[14];
  const float* cW  = (const float*)d_in[15];
  const float* cb  = (const float*)d_in[16];
  const float* uW  = (const float*)d_in[17];
  const float* ub  = (const float*)d_in[18];
  const float* vW  = (const float*)d_in[19];
  const float* vb  = (const float*)d_in[20];

  float* tbl = (float*)d_ws;        // 4096 x float4 = 64 KB
  float* out = (float*)d_out;

  dc_table<<<NBLK, NT, 0, stream>>>(zc, zt, bW0, bb0, bs0, bB0,
                                    bW1, bb1, bs1, bB1,
                                    tW0, tb0, tW1, tb1, cW, cb,
                                    uW, ub, vW, vb, tbl);
  dc_agents<<<NA / 256, 256, 0, stream>>>(xi, (const float4*)tbl, out);
}

// Round 4
// 122.761 us; speedup vs baseline: 1.1891x; 1.0521x over previous
//
#include <hip/hip_runtime.h>

#define NP      4096
#define WINDOW  327
#define HALF    163
#define RL      20
#define NA      262144
#define GN_EPS  1e-6f
#define R       8          // rows (bins) per block
#define NBLK    (NP / R)   // 512 blocks -> 2 blocks/CU
#define NT      512        // 8 waves/block -> 16 waves/CU = 4/SIMD

// fast tanh: 1 - 2/(e^{2x}+1), ~1e-7 abs err
__device__ __forceinline__ float tanh_fast(float x) {
  float e = __expf(2.0f * x);
  return 1.0f - 2.0f / (e + 1.0f);
}

// full-wave (64-lane) butterfly sum of two values
__device__ __forceinline__ void wave_sum2(float& a, float& b) {
#pragma unroll
  for (int m = 1; m < 64; m <<= 1) {
    a += __shfl_xor(a, m, 64);
    b += __shfl_xor(b, m, 64);
  }
}

// LDS layout (floats). part overlays espan+obsT (dead after L0, barrier-separated).
#define L_ESP   0               // espan[336]  (need 334; lifetime A..L0)
#define L_OBS   336             // obsT[40][8] (lifetime B..L0)
#define L_PART  0               // part[8][8][256] = 16384 (lifetime post-L0..GN1)
#define L_HBUF  16384           // hbuf[8][260] = 2080
#define L_HCL   18464           // hcL[8][36]  = 288
#define L_TOT   18752           // 75.0 KB -> 2 blocks/CU by LDS (matches grid/CU)

__global__ __launch_bounds__(NT, 4) void dc_table(
    const float* __restrict__ zc,  const float* __restrict__ zt,
    const float* __restrict__ bW0, const float* __restrict__ bb0,
    const float* __restrict__ bs0, const float* __restrict__ bB0,
    const float* __restrict__ bW1, const float* __restrict__ bb1,
    const float* __restrict__ bs1, const float* __restrict__ bB1,
    const float* __restrict__ tW0, const float* __restrict__ tb0,
    const float* __restrict__ tW1, const float* __restrict__ tb1,
    const float* __restrict__ cW,  const float* __restrict__ cb,
    const float* __restrict__ uW,  const float* __restrict__ ub,
    const float* __restrict__ vW,  const float* __restrict__ vb,
    float* __restrict__ tbl)
{
  __shared__ __align__(16) float sm[L_TOT];
  float* espan = sm + L_ESP;
  float* obsT  = sm + L_OBS;    // [k][r], stride 8
  float* part  = sm + L_PART;   // [w][r][f]
  float* hbuf  = sm + L_HBUF;   // [r][f], stride 260
  float* hcL   = sm + L_HCL;    // [r][c], stride 36

  const int tid = threadIdx.x;
  const int w   = tid >> 6;     // 0..7
  const int l   = tid & 63;
  const int s0  = blockIdx.x * R;

  // ---- Phase A: shared error span (edge-clamped), 334 elems ----
  if (tid < WINDOW + R - 1) {
    int c = s0 - HALF + tid;
    c = c < 0 ? 0 : (c > NP - 1 ? NP - 1 : c);
    espan[tid] = zc[c] - zt[c];
  }
  __syncthreads();

  // ---- Phase B: resize of err & gradient -> obsT[40][8]
  //      8 lanes per task; each lane sums ~4-5 taps; octet shuffle-reduce ----
  {
    const float INV  = (float)WINDOW / (float)RL;   // 16.35
    const float RINV = (float)RL / (float)WINDOW;
    const int sub = tid & 7;
    const int g8  = tid >> 3;                        // 0..63
#pragma unroll
    for (int it = 0; it < 5; ++it) {                 // 5*64 = 320 = R*2*RL tasks
      int task = it * 64 + g8;
      int q = task % (2 * RL);
      int r = task / (2 * RL);
      int qq = (q < RL) ? q : q - RL;
      float xs = ((float)qq + 0.5f) * INV - 0.5f;
      int jlo = (int)ceilf(xs - INV);  if (jlo < 0) jlo = 0;
      int jhi = (int)floorf(xs + INV); if (jhi > WINDOW - 1) jhi = WINDOW - 1;
      const float* p = espan + r;
      float wsum = 0.0f, vsum = 0.0f;
      for (int j = jlo + sub; j <= jhi; j += 8) {
        float wq = 1.0f - fabsf(xs - (float)j) * RINV;
        float v;
        if (q < RL) {
          v = p[j];
        } else {
          v = (j == 0) ? (p[1] - p[0]) :
              (j == WINDOW - 1) ? (p[WINDOW - 1] - p[WINDOW - 2]) :
              0.5f * (p[j + 1] - p[j - 1]);
        }
        wsum += wq;
        vsum += wq * v;
      }
#pragma unroll
      for (int m = 1; m < 8; m <<= 1) {              // octet-local reduce
        wsum += __shfl_xor(wsum, m, 64);
        vsum += __shfl_xor(vsum, m, 64);
      }
      if (sub == 0) obsT[q * 8 + r] = vsum / wsum;
    }
  }
  __syncthreads();

  float acc[R][4];

  // ---- Layer 0 (40 -> 256), k-split: wave w owns k in [5w, 5w+5) ----
#pragma unroll
  for (int r = 0; r < R; ++r) { acc[r][0]=0.f; acc[r][1]=0.f; acc[r][2]=0.f; acc[r][3]=0.f; }
  for (int kk = 0; kk < 5; ++kk) {
    int k = w * 5 + kk;
    float4 wt = *(const float4*)&bW0[k * 256 + 4 * l];
    float4 o0 = *(const float4*)&obsT[k * 8];
    float4 o1 = *(const float4*)&obsT[k * 8 + 4];
    const float wv[4] = {wt.x, wt.y, wt.z, wt.w};
    const float ov[8] = {o0.x, o0.y, o0.z, o0.w, o1.x, o1.y, o1.z, o1.w};
#pragma unroll
    for (int r = 0; r < R; ++r)
#pragma unroll
      for (int j = 0; j < 4; ++j) acc[r][j] = fmaf(ov[r], wv[j], acc[r][j]);
  }
  __syncthreads();   // espan/obsT reads complete before part overwrites them

  // ---- GN0 + tanh -> hbuf (single pass: wave w owns row w) ----
#pragma unroll
  for (int r = 0; r < R; ++r)
    *(float4*)&part[w * 2048 + r * 256 + 4 * l] = make_float4(acc[r][0], acc[r][1], acc[r][2], acc[r][3]);
  __syncthreads();
  {
    float4 b0 = *(const float4*)&bb0[4 * l];
    float val[4] = {b0.x, b0.y, b0.z, b0.w};
#pragma unroll
    for (int w2 = 0; w2 < 8; ++w2) {
      float4 p0 = *(const float4*)&part[w2 * 2048 + w * 256 + 4 * l];
      val[0]+=p0.x; val[1]+=p0.y; val[2]+=p0.z; val[3]+=p0.w;
    }
    float s = 0.f, q = 0.f;
#pragma unroll
    for (int i = 0; i < 4; ++i) { s += val[i]; q += val[i] * val[i]; }
    wave_sum2(s, q);
    float mu  = s * (1.0f / 256.0f);
    float var = fmaxf(q * (1.0f / 256.0f) - mu * mu, 0.0f);
    float rv  = rsqrtf(var + GN_EPS);
    float4 sc0 = *(const float4*)&bs0[4 * l];
    float4 sh0 = *(const float4*)&bB0[4 * l];
    const float sc[4] = {sc0.x,sc0.y,sc0.z,sc0.w};
    const float sh[4] = {sh0.x,sh0.y,sh0.z,sh0.w};
    float h[4];
#pragma unroll
    for (int i = 0; i < 4; ++i) h[i] = tanh_fast((val[i] - mu) * rv * sc[i] + sh[i]);
    *(float4*)&hbuf[w * 260 + 4 * l] = make_float4(h[0], h[1], h[2], h[3]);
  }
  __syncthreads();

  // ---- Layer 1 (256 -> 256), k-split: wave w owns k in [32w, 32w+32) ----
#pragma unroll
  for (int r = 0; r < R; ++r) { acc[r][0]=0.f; acc[r][1]=0.f; acc[r][2]=0.f; acc[r][3]=0.f; }
  for (int kk = 0; kk < 32; kk += 4) {
    int k0 = w * 32 + kk;
    float4 wt0 = *(const float4*)&bW1[(k0    ) * 256 + 4 * l];
    float4 wt1 = *(const float4*)&bW1[(k0 + 1) * 256 + 4 * l];
    float4 wt2 = *(const float4*)&bW1[(k0 + 2) * 256 + 4 * l];
    float4 wt3 = *(const float4*)&bW1[(k0 + 3) * 256 + 4 * l];
    float4 hr[R];
#pragma unroll
    for (int r = 0; r < R; ++r) hr[r] = *(const float4*)&hbuf[r * 260 + k0];
#pragma unroll
    for (int r = 0; r < R; ++r) {
      const float* hp = (const float*)&hr[r];
      acc[r][0] = fmaf(hp[0], wt0.x, acc[r][0]); acc[r][1] = fmaf(hp[0], wt0.y, acc[r][1]);
      acc[r][2] = fmaf(hp[0], wt0.z, acc[r][2]); acc[r][3] = fmaf(hp[0], wt0.w, acc[r][3]);
      acc[r][0] = fmaf(hp[1], wt1.x, acc[r][0]); acc[r][1] = fmaf(hp[1], wt1.y, acc[r][1]);
      acc[r][2] = fmaf(hp[1], wt1.z, acc[r][2]); acc[r][3] = fmaf(hp[1], wt1.w, acc[r][3]);
      acc[r][0] = fmaf(hp[2], wt2.x, acc[r][0]); acc[r][1] = fmaf(hp[2], wt2.y, acc[r][1]);
      acc[r][2] = fmaf(hp[2], wt2.z, acc[r][2]); acc[r][3] = fmaf(hp[2], wt2.w, acc[r][3]);
      acc[r][0] = fmaf(hp[3], wt3.x, acc[r][0]); acc[r][1] = fmaf(hp[3], wt3.y, acc[r][1]);
      acc[r][2] = fmaf(hp[3], wt3.z, acc[r][2]); acc[r][3] = fmaf(hp[3], wt3.w, acc[r][3]);
    }
  }

  // ---- GN1 + tanh -> hbuf (single pass; hbuf overwrite safe: all reads done pre-barrier) ----
#pragma unroll
  for (int r = 0; r < R; ++r)
    *(float4*)&part[w * 2048 + r * 256 + 4 * l] = make_float4(acc[r][0], acc[r][1], acc[r][2], acc[r][3]);
  __syncthreads();
  {
    float4 b0 = *(const float4*)&bb1[4 * l];
    float val[4] = {b0.x, b0.y, b0.z, b0.w};
#pragma unroll
    for (int w2 = 0; w2 < 8; ++w2) {
      float4 p0 = *(const float4*)&part[w2 * 2048 + w * 256 + 4 * l];
      val[0]+=p0.x; val[1]+=p0.y; val[2]+=p0.z; val[3]+=p0.w;
    }
    float s = 0.f, q = 0.f;
#pragma unroll
    for (int i = 0; i < 4; ++i) { s += val[i]; q += val[i] * val[i]; }
    wave_sum2(s, q);
    float mu  = s * (1.0f / 256.0f);
    float var = fmaxf(q * (1.0f / 256.0f) - mu * mu, 0.0f);
    float rv  = rsqrtf(var + GN_EPS);
    float4 sc0 = *(const float4*)&bs1[4 * l];
    float4 sh0 = *(const float4*)&bB1[4 * l];
    const float sc[4] = {sc0.x,sc0.y,sc0.z,sc0.w};
    const float sh[4] = {sh0.x,sh0.y,sh0.z,sh0.w};
    float h[4];
#pragma unroll
    for (int i = 0; i < 4; ++i) h[i] = tanh_fast((val[i] - mu) * rv * sc[i] + sh[i]);
    *(float4*)&hbuf[w * 260 + 4 * l] = make_float4(h[0], h[1], h[2], h[3]);
  }
  __syncthreads();

  // ---- Phase G: hcL[r][c..c+4) = cb + h1[r,:] . cW[:,c..c+4)  (wave w = row w)
  //      lane = (kg = l>>3, c4 = l&7); cW float4 rows (8 lanes = 128B contiguous);
  //      kg-staggered hbuf reads avoid same-bank serialization ----
  {
    int r  = w;
    int kg = l >> 3;
    int c  = (l & 7) * 4;
    float ga0 = 0.f, ga1 = 0.f, ga2 = 0.f, ga3 = 0.f;
#pragma unroll
    for (int ii = 0; ii < 8; ++ii) {
      int j  = (ii + kg) & 7;
      int kb = kg * 32 + 4 * j;
      float4 hv = *(const float4*)&hbuf[r * 260 + kb];
      const float hvv[4] = {hv.x, hv.y, hv.z, hv.w};
#pragma unroll
      for (int i2 = 0; i2 < 4; ++i2) {
        float4 cw = *(const float4*)&cW[(kb + i2) * 32 + c];
        ga0 = fmaf(hvv[i2], cw.x, ga0);
        ga1 = fmaf(hvv[i2], cw.y, ga1);
        ga2 = fmaf(hvv[i2], cw.z, ga2);
        ga3 = fmaf(hvv[i2], cw.w, ga3);
      }
    }
#pragma unroll
    for (int m = 8; m < 64; m <<= 1) {
      ga0 += __shfl_xor(ga0, m, 64);
      ga1 += __shfl_xor(ga1, m, 64);
      ga2 += __shfl_xor(ga2, m, 64);
      ga3 += __shfl_xor(ga3, m, 64);
    }
    if (l < 8) {
      float4 cbv = *(const float4*)&cb[c];
      *(float4*)&hcL[r * 36 + c] = make_float4(ga0 + cbv.x, ga1 + cbv.y, ga2 + cbv.z, ga3 + cbv.w);
    }
  }
  __syncthreads();

  // ---- Tail: 16 endpoint evals (8 bins x {left,right}), 8 threads each -> 2 waves ----
  if (tid < 128) {
    int v = tid >> 3, sub = tid & 7;
    int r = v >> 1, e = v & 1;
    int jg = s0 + r + e;                      // grid point; hc stays hcL[r]
    float xe = (float)jg * (1.0f / 4095.0f);
    float enc[8];
#pragma unroll
    for (int k = 0; k < 4; ++k) {
      float fr = (float)(1 << k);
      float a = (xe * fr) * 3.14159265358979f;
      enc[k]     = sinf(a);
      enc[k + 4] = cosf(a);
    }
    int base = (tid & 63) & ~7;               // octet base lane within wave

    float t0v[4];
#pragma unroll
    for (int i = 0; i < 4; ++i) {
      int f = 4 * sub + i;
      float a = tb0[f];
#pragma unroll
      for (int k = 0; k < 8; ++k) a = fmaf(enc[k], tW0[k * 32 + f], a);
      t0v[i] = tanh_fast(a);
    }

    float t1v[4];
#pragma unroll
    for (int i = 0; i < 4; ++i) t1v[i] = tb1[4 * sub + i];
#pragma unroll
    for (int j8 = 0; j8 < 8; ++j8) {
#pragma unroll
      for (int i2 = 0; i2 < 4; ++i2) {
        float tv = __shfl(t0v[i2], base + j8, 64);
        int k = 4 * j8 + i2;
#pragma unroll
        for (int i = 0; i < 4; ++i) t1v[i] = fmaf(tv, tW1[k * 32 + 4 * sub + i], t1v[i]);
      }
    }
#pragma unroll
    for (int i = 0; i < 4; ++i) t1v[i] = tanh_fast(t1v[i]);

    float xvv[4];
#pragma unroll
    for (int i = 0; i < 4; ++i) xvv[i] = hcL[r * 36 + 4 * sub + i];
#pragma unroll
    for (int j8 = 0; j8 < 8; ++j8) {
#pragma unroll
      for (int i2 = 0; i2 < 4; ++i2) {
        float tv = __shfl(t1v[i2], base + j8, 64);
        int k = 4 * j8 + i2;
#pragma unroll
        for (int i = 0; i < 4; ++i) xvv[i] = fmaf(tv, cW[(256 + k) * 32 + 4 * sub + i], xvv[i]);
      }
    }
#pragma unroll
    for (int i = 0; i < 4; ++i) xvv[i] = tanh_fast(xvv[i]);

    float up = 0.f, vp = 0.f;
#pragma unroll
    for (int i = 0; i < 4; ++i) {
      up = fmaf(xvv[i], uW[4 * sub + i], up);
      vp = fmaf(xvv[i], vW[4 * sub + i], vp);
    }
#pragma unroll
    for (int m = 1; m < 8; m <<= 1) {
      up += __shfl_xor(up, m, 64);
      vp += __shfl_xor(vp, m, 64);
    }
    if (sub == 0) {
      int s = s0 + r;
      tbl[4 * s + e]     = 40.0f * tanh_fast(up + ub[0]);
      tbl[4 * s + 2 + e] = tanh_fast(vp + vb[0]);
    }
  }
}

// ---------------- Kernel 2: agents = bin + lerp ----------------
__global__ __launch_bounds__(256) void dc_agents(
    const float* __restrict__ xi_curr, const float4* __restrict__ tbl,
    float* __restrict__ out)
{
  int a = blockIdx.x * 256 + threadIdx.x;
  float xi = xi_curr[a];
  float p = xi * 4095.0f;           // same fp32 product the reference truncates
  int s = (int)p;
  s = s > 4095 ? 4095 : s;
  float t = p - (float)s;           // exact (Sterbenz)
  float4 tb = tbl[s];               // {u_l, u_r, v_l, v_r}
  out[a]      = fmaf(t, tb.y - tb.x, tb.x);
  out[NA + a] = fmaf(t, tb.w - tb.z, tb.z);
}

extern "C" void kernel_launch(void* const* d_in, const int* in_sizes, int n_in,
                              void* d_out, int out_size, void* d_ws, size_t ws_size,
                              hipStream_t stream) {
  const float* zc  = (const float*)d_in[0];
  const float* zt  = (const float*)d_in[1];
  const float* xi  = (const float*)d_in[2];
  const float* bW0 = (const float*)d_in[3];
  const float* bb0 = (const float*)d_in[4];
  const float* bs0 = (const float*)d_in[5];
  const float* bB0 = (const float*)d_in[6];
  const float* bW1 = (const float*)d_in[7];
  const float* bb1 = (const float*)d_in[8];
  const float* bs1 = (const float*)d_in[9];
  const float* bB1 = (const float*)d_in[10];
  const float* tW0 = (const float*)d_in[11];
  const float* tb0 = (const float*)d_in[12];
  const float* tW1 = (const float*)d_in[13];
  const float* tb1 = (const float*)d_in[14];
  const float* cW  = (const float*)d_in[15];
  const float* cb  = (const float*)d_in[16];
  const float* uW  = (const float*)d_in[17];
  const float* ub  = (const float*)d_in[18];
  const float* vW  = (const float*)d_in[19];
  const float* vb  = (const float*)d_in[20];

  float* tbl = (float*)d_ws;        // 4096 x float4 = 64 KB
  float* out = (float*)d_out;

  dc_table<<<NBLK, NT, 0, stream>>>(zc, zt, bW0, bb0, bs0, bB0,
                                    bW1, bb1, bs1, bB1,
                                    tW0, tb0, tW1, tb1, cW, cb,
                                    uW, ub, vW, vb, tbl);
  dc_agents<<<NA / 256, 256, 0, stream>>>(xi, (const float4*)tbl, out);
}